// Round 1
// baseline (304.494 us; speedup 1.0000x reference)
//
#include <hip/hip_runtime.h>
#include <math.h>

// Problem constants (B=8, F=32 -> 256 frames of 224x224x3 f32)
#define NFRAMES 256
#define NH 224
#define NW 224
#define NPIX (NH * NW)            // 50176
#define NOISE_LEN 766             // 3*L - 2
#define WIN_LEN 511               // 2*L - 1
#define BLOCKS_PER_FRAME (NPIX / 256)  // 196

// ---------------------------------------------------------------------------
// Kernel 1: smooth the noise, build per-frame homographies M (256 x 3 x 3).
// One block, 256 threads; thread l owns frame l. All math in f64 (cost ~4 us)
// so the tolerance budget is spent in the sampling kernel, not here.
// ---------------------------------------------------------------------------
__global__ __launch_bounds__(256) void build_mats_kernel(
    const float* __restrict__ noise,   // (4, 766)
    const float* __restrict__ basis,   // (4, 3, 3)
    float* __restrict__ Mout) {        // (256, 9)
  __shared__ double wsh[WIN_LEN];
  __shared__ float nsh[4 * NOISE_LEN];
  __shared__ double Ssum;
  const int t = threadIdx.x;

  for (int i = t; i < 4 * NOISE_LEN; i += 256) nsh[i] = noise[i];
  // w[k] = 1.1^(255 - |k-255|)  (symmetric exponential window)
  for (int i = t; i < WIN_LEN; i += 256) {
    int e = 255 - abs(i - 255);
    wsh[i] = pow(1.1, (double)e);
  }
  __syncthreads();
  if (t == 0) {
    double s = 0.0;
    for (int i = 0; i < WIN_LEN; ++i) s += wsh[i];
    Ssum = s;
  }
  __syncthreads();
  const double S = Ssum;

  // vals[j][t] = (1/S) * sum_k noise[j][t+k] * w[k]   (conv == corr, w symmetric)
  double wv[4];
  for (int j = 0; j < 4; ++j) {
    const float* row = nsh + j * NOISE_LEN;
    double acc = 0.0;
    for (int k = 0; k < WIN_LEN; ++k) acc = fma((double)row[t + k], wsh[k], acc);
    double v = acc / S;
    wv[j] = v > 0.0 ? v : 0.0;   // relu
  }

  // warp = sum_j wv[j]*B_j + (4 - sum wv)*I
  double warp[9];
  const double swv = wv[0] + wv[1] + wv[2] + wv[3];
  #pragma unroll
  for (int e = 0; e < 9; ++e) {
    double acc = 0.0;
    #pragma unroll
    for (int j = 0; j < 4; ++j) acc += wv[j] * (double)basis[j * 9 + e];
    warp[e] = acc;
  }
  warp[0] += 4.0 - swv;
  warp[4] += 4.0 - swv;
  warp[8] += 4.0 - swv;

  // M = [S(h-1,w-1) @ T(.5,.5)] @ warp @ [T(-.5,-.5) @ S(1/(h-1),1/(w-1))]
  // A    = [[W1,0,.5*W1],[0,H1,.5*H1],[0,0,1]]
  // Binv = [[1/W1,0,-.5],[0,1/H1,-.5],[0,0,1]]
  const double W1 = (double)(NW - 1);
  const double H1 = (double)(NH - 1);
  double T[9];
  #pragma unroll
  for (int c = 0; c < 3; ++c) {
    T[0 * 3 + c] = W1 * warp[0 * 3 + c] + 0.5 * W1 * warp[2 * 3 + c];
    T[1 * 3 + c] = H1 * warp[1 * 3 + c] + 0.5 * H1 * warp[2 * 3 + c];
    T[2 * 3 + c] = warp[2 * 3 + c];
  }
  float Mo[9];
  #pragma unroll
  for (int r = 0; r < 3; ++r) {
    Mo[r * 3 + 0] = (float)(T[r * 3 + 0] / W1);
    Mo[r * 3 + 1] = (float)(T[r * 3 + 1] / H1);
    Mo[r * 3 + 2] = (float)(-0.5 * T[r * 3 + 0] - 0.5 * T[r * 3 + 1] + T[r * 3 + 2]);
  }
  #pragma unroll
  for (int e = 0; e < 9; ++e) Mout[t * 9 + e] = Mo[e];
}

// ---------------------------------------------------------------------------
// Kernel 2: per-pixel projective warp + bilinear sample (branchless validity,
// matching reference: validity tested on un-clipped float corner coords,
// clip-then-truncate for indices, zero fill outside).
// ---------------------------------------------------------------------------
__global__ __launch_bounds__(256) void warp_bilinear_kernel(
    const float* __restrict__ x,     // (256, 224, 224, 3)
    const float* __restrict__ M,     // (256, 9)
    float* __restrict__ out) {       // (256, 224, 224, 3)
  const int bid = blockIdx.x;
  const int l = bid / BLOCKS_PER_FRAME;                      // frame (block-uniform)
  const int p = (bid - l * BLOCKS_PER_FRAME) * 256 + threadIdx.x;  // pixel in frame

  const float* Mp = M + l * 9;   // uniform -> scalar loads
  const float m00 = Mp[0], m01 = Mp[1], m02 = Mp[2];
  const float m10 = Mp[3], m11 = Mp[4], m12 = Mp[5];
  const float m20 = Mp[6], m21 = Mp[7], m22 = Mp[8];

  const int r = p / NW;
  const int c = p - r * NW;
  const float cf = (float)c, rf = (float)r;

  const float fx = fmaf(m00, cf, fmaf(m01, rf, m02));
  const float fy = fmaf(m10, cf, fmaf(m11, rf, m12));
  const float fz = fmaf(m20, cf, fmaf(m21, rf, m22));
  const float inv = __builtin_amdgcn_rcpf(fz);   // ~2^-22 rel err, well in budget
  const float xs = fx * inv;
  const float ys = fy * inv;

  const float x0f = floorf(xs), y0f = floorf(ys);
  const float wx = xs - x0f, wy = ys - y0f;
  const float x1f = x0f + 1.0f, y1f = y0f + 1.0f;

  const float vx0 = (x0f >= 0.0f && x0f <= (float)(NW - 1)) ? 1.0f : 0.0f;
  const float vx1 = (x1f >= 0.0f && x1f <= (float)(NW - 1)) ? 1.0f : 0.0f;
  const float vy0 = (y0f >= 0.0f && y0f <= (float)(NH - 1)) ? 1.0f : 0.0f;
  const float vy1 = (y1f >= 0.0f && y1f <= (float)(NH - 1)) ? 1.0f : 0.0f;

  const int xi0 = (int)fminf(fmaxf(x0f, 0.0f), (float)(NW - 1));
  const int xi1 = (int)fminf(fmaxf(x1f, 0.0f), (float)(NW - 1));
  const int yi0 = (int)fminf(fmaxf(y0f, 0.0f), (float)(NH - 1));
  const int yi1 = (int)fminf(fmaxf(y1f, 0.0f), (float)(NH - 1));

  const float* img = x + (size_t)l * (NPIX * 3);
  const float* p00 = img + (yi0 * NW + xi0) * 3;
  const float* p01 = img + (yi0 * NW + xi1) * 3;
  const float* p10 = img + (yi1 * NW + xi0) * 3;
  const float* p11 = img + (yi1 * NW + xi1) * 3;

  const float w00 = (1.0f - wy) * (1.0f - wx) * vy0 * vx0;
  const float w01 = (1.0f - wy) * wx * vy0 * vx1;
  const float w10 = wy * (1.0f - wx) * vy1 * vx0;
  const float w11 = wy * wx * vy1 * vx1;

  const float o0 = w00 * p00[0] + w01 * p01[0] + w10 * p10[0] + w11 * p11[0];
  const float o1 = w00 * p00[1] + w01 * p01[1] + w10 * p10[1] + w11 * p11[1];
  const float o2 = w00 * p00[2] + w01 * p01[2] + w10 * p10[2] + w11 * p11[2];

  float* op = out + ((size_t)l * NPIX + p) * 3;
  op[0] = o0;
  op[1] = o1;
  op[2] = o2;
}

extern "C" void kernel_launch(void* const* d_in, const int* in_sizes, int n_in,
                              void* d_out, int out_size, void* d_ws, size_t ws_size,
                              hipStream_t stream) {
  (void)in_sizes; (void)n_in; (void)out_size; (void)ws_size;
  const float* x     = (const float*)d_in[0];   // (8,32,224,224,3) f32
  const float* noise = (const float*)d_in[1];   // (4,766) f32
  const float* basis = (const float*)d_in[2];   // (4,3,3) f32
  float* out  = (float*)d_out;
  float* Mbuf = (float*)d_ws;                   // 256*9 floats scratch

  build_mats_kernel<<<1, 256, 0, stream>>>(noise, basis, Mbuf);
  warp_bilinear_kernel<<<NFRAMES * BLOCKS_PER_FRAME, 256, 0, stream>>>(x, Mbuf, out);
}

// Round 2
// 263.976 us; speedup vs baseline: 1.1535x; 1.1535x over previous
//
#include <hip/hip_runtime.h>
#include <math.h>

// Problem constants (B=8, F=32 -> 256 frames of 224x224x3 f32)
#define NFRAMES 256
#define NH 224
#define NW 224
#define NPIX (NH * NW)            // 50176
#define NOISE_LEN 766             // 3*L - 2
#define WIN_LEN 511               // 2*L - 1
#define BLOCKS_PER_FRAME (NPIX / 256)  // 196

// ---------------------------------------------------------------------------
// Kernel 1 (v2): one block per frame (256 blocks -> one per CU).
// Wave j (4 waves) computes the 511-tap convolution for noise row j at output
// position b: 8 taps per lane in f64, then a 64-lane shuffle reduction.
// Window normalization S via closed-form geometric series (no serial loop).
// Thread 0 composes the 3x3 homography in f64 and writes 9 floats.
// ---------------------------------------------------------------------------
__global__ __launch_bounds__(256) void build_mats_v2(
    const float* __restrict__ noise,   // (4, 766)
    const float* __restrict__ basis,   // (4, 3, 3)
    float* __restrict__ Mout) {        // (256, 9)
  const int b = blockIdx.x;      // frame index
  const int t = threadIdx.x;
  const int j = t >> 6;          // noise row (wave id)
  const int lane = t & 63;

  __shared__ double wsh[WIN_LEN];
  __shared__ double vsh[4];

  // weights w[k] = 1.1^(255 - |k-255|), k = 0..510
  for (int k = t; k < WIN_LEN; k += 256) {
    int e = 255 - abs(k - 255);
    wsh[k] = pow(1.1, (double)e);
  }
  __syncthreads();

  // sum(w) closed form: sum_{e=0}^{254} 1.1^e + sum_{e=0}^{255} 1.1^e
  const double S = (pow(1.1, 255.0) - 1.0) * 10.0 + (pow(1.1, 256.0) - 1.0) * 10.0;

  // conv (valid) at position b for row j: sum_{k=0}^{510} n[j][b+k] * w[k]
  const float* row = noise + j * NOISE_LEN + b;
  const int k0 = lane * 8;
  double acc = 0.0;
  #pragma unroll
  for (int i = 0; i < 8; ++i) {
    const int k = k0 + i;
    if (k < WIN_LEN) acc = fma((double)row[k], wsh[k], acc);
  }
  #pragma unroll
  for (int off = 32; off > 0; off >>= 1) acc += __shfl_down(acc, off, 64);
  if (lane == 0) {
    const double v = acc / S;
    vsh[j] = v > 0.0 ? v : 0.0;   // relu
  }
  __syncthreads();

  if (t == 0) {
    const double wv0 = vsh[0], wv1 = vsh[1], wv2 = vsh[2], wv3 = vsh[3];
    const double swv = wv0 + wv1 + wv2 + wv3;
    double warp[9];
    #pragma unroll
    for (int e = 0; e < 9; ++e) {
      warp[e] = wv0 * (double)basis[0 * 9 + e] + wv1 * (double)basis[1 * 9 + e] +
                wv2 * (double)basis[2 * 9 + e] + wv3 * (double)basis[3 * 9 + e];
    }
    warp[0] += 4.0 - swv;
    warp[4] += 4.0 - swv;
    warp[8] += 4.0 - swv;

    // M = [S(h-1,w-1) @ T(.5,.5)] @ warp @ [T(-.5,-.5) @ S(1/(h-1),1/(w-1))]
    const double W1 = (double)(NW - 1);
    const double H1 = (double)(NH - 1);
    double T[9];
    #pragma unroll
    for (int c = 0; c < 3; ++c) {
      T[0 * 3 + c] = W1 * warp[0 * 3 + c] + 0.5 * W1 * warp[2 * 3 + c];
      T[1 * 3 + c] = H1 * warp[1 * 3 + c] + 0.5 * H1 * warp[2 * 3 + c];
      T[2 * 3 + c] = warp[2 * 3 + c];
    }
    float* Mo = Mout + b * 9;
    #pragma unroll
    for (int r = 0; r < 3; ++r) {
      Mo[r * 3 + 0] = (float)(T[r * 3 + 0] / W1);
      Mo[r * 3 + 1] = (float)(T[r * 3 + 1] / H1);
      Mo[r * 3 + 2] = (float)(-0.5 * T[r * 3 + 0] - 0.5 * T[r * 3 + 1] + T[r * 3 + 2]);
    }
  }
}

// ---------------------------------------------------------------------------
// Kernel 2: per-pixel projective warp + bilinear sample (branchless validity,
// matching reference: validity tested on un-clipped float corner coords,
// clip-then-truncate for indices, zero fill outside). Nontemporal output
// stores: out is never re-read, keep L2 for the gather working set.
// ---------------------------------------------------------------------------
__global__ __launch_bounds__(256) void warp_bilinear_kernel(
    const float* __restrict__ x,     // (256, 224, 224, 3)
    const float* __restrict__ M,     // (256, 9)
    float* __restrict__ out) {       // (256, 224, 224, 3)
  const int bid = blockIdx.x;
  const int l = bid / BLOCKS_PER_FRAME;                      // frame (block-uniform)
  const int p = (bid - l * BLOCKS_PER_FRAME) * 256 + threadIdx.x;  // pixel in frame

  const float* Mp = M + l * 9;   // uniform -> scalar loads
  const float m00 = Mp[0], m01 = Mp[1], m02 = Mp[2];
  const float m10 = Mp[3], m11 = Mp[4], m12 = Mp[5];
  const float m20 = Mp[6], m21 = Mp[7], m22 = Mp[8];

  const int r = p / NW;
  const int c = p - r * NW;
  const float cf = (float)c, rf = (float)r;

  const float fx = fmaf(m00, cf, fmaf(m01, rf, m02));
  const float fy = fmaf(m10, cf, fmaf(m11, rf, m12));
  const float fz = fmaf(m20, cf, fmaf(m21, rf, m22));
  const float inv = __builtin_amdgcn_rcpf(fz);   // ~2^-22 rel err, in budget
  const float xs = fx * inv;
  const float ys = fy * inv;

  const float x0f = floorf(xs), y0f = floorf(ys);
  const float wx = xs - x0f, wy = ys - y0f;
  const float x1f = x0f + 1.0f, y1f = y0f + 1.0f;

  const float vx0 = (x0f >= 0.0f && x0f <= (float)(NW - 1)) ? 1.0f : 0.0f;
  const float vx1 = (x1f >= 0.0f && x1f <= (float)(NW - 1)) ? 1.0f : 0.0f;
  const float vy0 = (y0f >= 0.0f && y0f <= (float)(NH - 1)) ? 1.0f : 0.0f;
  const float vy1 = (y1f >= 0.0f && y1f <= (float)(NH - 1)) ? 1.0f : 0.0f;

  const int xi0 = (int)fminf(fmaxf(x0f, 0.0f), (float)(NW - 1));
  const int xi1 = (int)fminf(fmaxf(x1f, 0.0f), (float)(NW - 1));
  const int yi0 = (int)fminf(fmaxf(y0f, 0.0f), (float)(NH - 1));
  const int yi1 = (int)fminf(fmaxf(y1f, 0.0f), (float)(NH - 1));

  const float* img = x + (size_t)l * (NPIX * 3);
  const float* p00 = img + (yi0 * NW + xi0) * 3;
  const float* p01 = img + (yi0 * NW + xi1) * 3;
  const float* p10 = img + (yi1 * NW + xi0) * 3;
  const float* p11 = img + (yi1 * NW + xi1) * 3;

  const float w00 = (1.0f - wy) * (1.0f - wx) * vy0 * vx0;
  const float w01 = (1.0f - wy) * wx * vy0 * vx1;
  const float w10 = wy * (1.0f - wx) * vy1 * vx0;
  const float w11 = wy * wx * vy1 * vx1;

  const float o0 = w00 * p00[0] + w01 * p01[0] + w10 * p10[0] + w11 * p11[0];
  const float o1 = w00 * p00[1] + w01 * p01[1] + w10 * p10[1] + w11 * p11[1];
  const float o2 = w00 * p00[2] + w01 * p01[2] + w10 * p10[2] + w11 * p11[2];

  float* op = out + ((size_t)l * NPIX + p) * 3;
  __builtin_nontemporal_store(o0, op + 0);
  __builtin_nontemporal_store(o1, op + 1);
  __builtin_nontemporal_store(o2, op + 2);
}

extern "C" void kernel_launch(void* const* d_in, const int* in_sizes, int n_in,
                              void* d_out, int out_size, void* d_ws, size_t ws_size,
                              hipStream_t stream) {
  (void)in_sizes; (void)n_in; (void)out_size; (void)ws_size;
  const float* x     = (const float*)d_in[0];   // (8,32,224,224,3) f32
  const float* noise = (const float*)d_in[1];   // (4,766) f32
  const float* basis = (const float*)d_in[2];   // (4,3,3) f32
  float* out  = (float*)d_out;
  float* Mbuf = (float*)d_ws;                   // 256*9 floats scratch

  build_mats_v2<<<NFRAMES, 256, 0, stream>>>(noise, basis, Mbuf);
  warp_bilinear_kernel<<<NFRAMES * BLOCKS_PER_FRAME, 256, 0, stream>>>(x, Mbuf, out);
}